// Round 4
// baseline (874.526 us; speedup 1.0000x reference)
//
#include <hip/hip_runtime.h>

// InteractionBlock (MACE-style) on MI355X — round 4: decoupled MLP.
// R3 post-mortem: fused k_gather 742us at VALUBusy 45%, HBM 4% — MLP inner
// loop bound by LDS b128 reads + weight re-streaming amortized over only 4
// edges. Fix: separate k_mlp (4 threads/edge, h[64] in VGPRs, weights via
// scalar loads from transposed table, zero LDS) writing tpw[e][320] fp32 to
// ws; k_gather2 just streams tpw + sup/vup and accumulates messages.
// Fallback to the R3 fused path if ws_size < ~433MB.
//
// ws layout: ints[deg nN | offs nN+1 | cursor nN | eidx nE] then floats
// [cw 71808 | cwT 29184 | sup nN*64 | vup nN*192 | flag | pad | tpw nE*320]

typedef unsigned short u16;
typedef unsigned int u32;

#define CW_UP0 0
#define CW_UP1 4096
#define CW_M1  8192
#define CW_M2  8704
#define CW_M3  12800
#define CW_M4  16896
#define CW_L0  37376
#define CW_L1  45568
#define CW_P0  57856
#define CW_P1  61952
#define CW_S01 66048
#define CW_S02 66688
#define CW_S03 67968
#define CW_S11 69248
#define CW_S12 69888
#define CW_S13 70528
#define CW_TOTAL 71808

// transposed MLP weights (row-contiguous columns), appended after cw
#define CT_M1 0
#define CT_M2 512
#define CT_M3 4608
#define CT_M4 8704
#define CT_TOTAL 29184

#define C_SILU     1.6765224f
#define INV_SQRT3  0.57735027f
#define INV_SQRT2  0.70710678f

__device__ __forceinline__ float b2f(u16 u) {
  union { u32 i; float f; } x; x.i = ((u32)u) << 16; return x.f;
}
__device__ __forceinline__ u16 f2b(float f) {
  union { float f; u32 i; } x; x.f = f;
  u32 i = x.i;
  u32 r = (i + 0x7fffu + ((i >> 16) & 1u)) >> 16;
  return (u16)r;
}
__device__ __forceinline__ float ldf(const void* p, size_t i, int f32) {
  return f32 ? ((const float*)p)[i] : b2f(((const u16*)p)[i]);
}
__device__ __forceinline__ float silu_n(float x) {
  return C_SILU * x / (1.0f + __expf(-x));
}

// ---- dtype detector
__global__ void k_detect(const void* nf, int* flag) {
  __shared__ int cnt;
  if (threadIdx.x == 0) cnt = 0;
  __syncthreads();
  const u16* p = (const u16*)nf;
  int wild = 0;
  for (int i = threadIdx.x; i < 4096; i += 256) {
    float ax = fabsf(b2f(p[i]));
    if (!(ax <= 1e10f) || (ax != 0.f && ax < 1e-10f)) wild++;
  }
  atomicAdd(&cnt, wild);
  __syncthreads();
  if (threadIdx.x == 0) *flag = (cnt > 100) ? 1 : 0;
}

struct WPtrs { const void* p[16]; };

__global__ __launch_bounds__(256) void k_prep(WPtrs wp, float* __restrict__ cw,
                                              const int* __restrict__ flagp) {
  const int   sizes[16]  = {4096,4096,512,4096,4096,20480,8192,12288,4096,4096,
                            640,1280,1280,640,640,1280};
  const float scales[16] = {0.125f,0.125f,0.35355339f,0.125f,0.125f,0.125f,
                            0.08838835f,0.07216878f,0.125f,0.125f,
                            1.f,1.f,1.f,1.f,1.f,1.f};
  const int f32 = *flagp;
  int gid = blockIdx.x * 256 + threadIdx.x;
  if (gid >= CW_TOTAL) return;
  int off = gid, seg = 0;
  while (off >= sizes[seg]) { off -= sizes[seg]; seg++; }
  cw[gid] = ldf(wp.p[seg], off, f32) * scales[seg];
}

// transpose MLP weights: cwT[o-major] from cw (after k_prep)
__global__ __launch_bounds__(256) void k_prepT(float* __restrict__ cw) {
  float* cT = cw + CW_TOTAL;
  int gid = blockIdx.x * 256 + threadIdx.x;
  if (gid >= CT_TOTAL) return;
  float v;
  if (gid < CT_M2) {                     // M1: [o*8+b] <- [b*64+o]
    int t = gid - CT_M1, o = t >> 3, b = t & 7;
    v = cw[CW_M1 + b * 64 + o];
  } else if (gid < CT_M3) {              // M2: [o*64+k] <- [k*64+o]
    int t = gid - CT_M2, o = t >> 6, k = t & 63;
    v = cw[CW_M2 + k * 64 + o];
  } else if (gid < CT_M4) {              // M3
    int t = gid - CT_M3, o = t >> 6, k = t & 63;
    v = cw[CW_M3 + k * 64 + o];
  } else {                               // M4: [o*64+k] <- [k*320+o]
    int t = gid - CT_M4, o = t >> 6, k = t & 63;
    v = cw[CW_M4 + k * 320 + o];
  }
  cT[gid] = v;
}

// ---- CSR build
__global__ __launch_bounds__(256) void k_hist(const int* __restrict__ je,
                                              int* __restrict__ deg, int nE) {
  int e = blockIdx.x * 256 + threadIdx.x;
  if (e < nE) atomicAdd(&deg[je[e]], 1);
}

__global__ __launch_bounds__(256) void k_scan(const int* __restrict__ deg,
                                              int* __restrict__ offs,
                                              int* __restrict__ cursor, int nN) {
  __shared__ int part[256];
  int t = threadIdx.x;
  int per = (nN + 255) / 256;
  int lo = t * per, hi = (t + 1) * per; if (hi > nN) hi = nN;
  int s = 0;
  for (int i = lo; i < hi; i++) s += deg[i];
  part[t] = s;
  __syncthreads();
  if (t == 0) {
    int run = 0;
    for (int i = 0; i < 256; i++) { int v = part[i]; part[i] = run; run += v; }
    offs[nN] = run;
  }
  __syncthreads();
  int run = part[t];
  for (int i = lo; i < hi; i++) {
    offs[i] = run; cursor[i] = run; run += deg[i];
  }
}

__global__ __launch_bounds__(256) void k_scatter(const int* __restrict__ je,
                                                 int* __restrict__ cursor,
                                                 int* __restrict__ eidx, int nE) {
  int e = blockIdx.x * 256 + threadIdx.x;
  if (e < nE) {
    int pos = atomicAdd(&cursor[je[e]], 1);
    eidx[pos] = e;
  }
}

// ---- node up-projection: sup fp32, vup fp32 planar [(n*3+m)*64+l]
__global__ __launch_bounds__(256) void k_node_up(
    const void* __restrict__ nf, const float* __restrict__ cw,
    float* __restrict__ sup, float* __restrict__ vup, int nN,
    const int* __restrict__ flagp) {
  __shared__ float row[4][256];
  const int f32 = *flagp;
  int w = threadIdx.x >> 6, l = threadIdx.x & 63;
  int n = blockIdx.x * 4 + w;
  bool valid = n < nN;
  int nn = valid ? n : 0;
#pragma unroll
  for (int t = 0; t < 4; t++)
    row[w][t * 64 + l] = ldf(nf, (size_t)nn * 256 + t * 64 + l, f32);
  __syncthreads();
  float sacc = 0.f, v0 = 0.f, v1 = 0.f, v2 = 0.f;
#pragma unroll 8
  for (int c = 0; c < 64; c++) {
    float w0 = cw[CW_UP0 + c * 64 + l];
    float w1 = cw[CW_UP1 + c * 64 + l];
    sacc += row[w][c] * w0;
    v0 += row[w][64 + c * 3 + 0] * w1;
    v1 += row[w][64 + c * 3 + 1] * w1;
    v2 += row[w][64 + c * 3 + 2] * w1;
  }
  if (valid) {
    sup[(size_t)n * 64 + l] = sacc;
    vup[((size_t)n * 3 + 0) * 64 + l] = v0;
    vup[((size_t)n * 3 + 1) * 64 + l] = v1;
    vup[((size_t)n * 3 + 2) * 64 + l] = v2;
  }
}

// ---- edge MLP: 4 threads per edge, h[64] in VGPRs, scalar weights, no LDS.
// Lane q = tid&3 computes outs [q*16, q*16+16) per layer; __shfl exchange.
__global__ __launch_bounds__(256) void k_mlp(
    const void* __restrict__ ef, const float* __restrict__ cw,
    float* __restrict__ tpw, int nE, const int* __restrict__ flagp) {
  const int f32 = *flagp;
  int tid = threadIdx.x;
  int l = tid & 63;
  int q = tid & 3;
  int gt = blockIdx.x * 256 + tid;
  int e = gt >> 2;
  bool valid = e < nE;
  int ec = valid ? e : (nE - 1);
  const float* cT = cw + CW_TOTAL;

  // load edge feats (8), all 4 lanes of the group load the same row
  float ev[8];
  if (f32) {
    const float4* p = (const float4*)ef;
    float4 q0 = p[(size_t)ec * 2], q1 = p[(size_t)ec * 2 + 1];
    ev[0]=q0.x; ev[1]=q0.y; ev[2]=q0.z; ev[3]=q0.w;
    ev[4]=q1.x; ev[5]=q1.y; ev[6]=q1.z; ev[7]=q1.w;
  } else {
    const uint4* p = (const uint4*)ef;
    uint4 r = p[ec];
    ev[0]=b2f(r.x & 0xffff); ev[1]=b2f(r.x >> 16);
    ev[2]=b2f(r.y & 0xffff); ev[3]=b2f(r.y >> 16);
    ev[4]=b2f(r.z & 0xffff); ev[5]=b2f(r.z >> 16);
    ev[6]=b2f(r.w & 0xffff); ev[7]=b2f(r.w >> 16);
  }

  float h[64];
  float hn[16];
  int grp = l & 0x3C;   // shuffle group base (4 lanes per edge)

  // layer 1: 8 -> 64 (16 outs per lane)
  {
    const float* wr = cT + CT_M1 + (q * 16) * 8;
#pragma unroll
    for (int j = 0; j < 16; j++) {
      float a = 0.f;
#pragma unroll
      for (int b = 0; b < 8; b++) a += ev[b] * wr[j * 8 + b];
      hn[j] = silu_n(a);
    }
  }
#pragma unroll
  for (int j = 0; j < 4; j++)
#pragma unroll
    for (int t = 0; t < 16; t++)
      h[j * 16 + t] = __shfl(hn[t], grp | j, 64);

  // layer 2: 64 -> 64
  {
    const float* wr = cT + CT_M2 + (q * 16) * 64;
#pragma unroll
    for (int j = 0; j < 16; j++) hn[j] = 0.f;
#pragma unroll
    for (int k = 0; k < 64; k++) {
      float hk = h[k];
#pragma unroll
      for (int j = 0; j < 16; j++) hn[j] += hk * wr[j * 64 + k];
    }
#pragma unroll
    for (int j = 0; j < 16; j++) hn[j] = silu_n(hn[j]);
  }
#pragma unroll
  for (int j = 0; j < 4; j++)
#pragma unroll
    for (int t = 0; t < 16; t++)
      h[j * 16 + t] = __shfl(hn[t], grp | j, 64);

  // layer 3: 64 -> 64
  {
    const float* wr = cT + CT_M3 + (q * 16) * 64;
#pragma unroll
    for (int j = 0; j < 16; j++) hn[j] = 0.f;
#pragma unroll
    for (int k = 0; k < 64; k++) {
      float hk = h[k];
#pragma unroll
      for (int j = 0; j < 16; j++) hn[j] += hk * wr[j * 64 + k];
    }
#pragma unroll
    for (int j = 0; j < 16; j++) hn[j] = silu_n(hn[j]);
  }
#pragma unroll
  for (int j = 0; j < 4; j++)
#pragma unroll
    for (int t = 0; t < 16; t++)
      h[j * 16 + t] = __shfl(hn[t], grp | j, 64);

  // layer 4: 64 -> 320, no activation; store tpw[e][g*64 + q*16 + j]
  for (int g = 0; g < 5; g++) {
    const float* wr = cT + CT_M4 + (size_t)(g * 64 + q * 16) * 64;
    float acc[16];
#pragma unroll
    for (int j = 0; j < 16; j++) acc[j] = 0.f;
#pragma unroll
    for (int k = 0; k < 64; k++) {
      float hk = h[k];
#pragma unroll
      for (int j = 0; j < 16; j++) acc[j] += hk * wr[j * 64 + k];
    }
    if (valid) {
      float4* dst = (float4*)(tpw + (size_t)e * 320 + g * 64 + q * 16);
      dst[0] = make_float4(acc[0], acc[1], acc[2], acc[3]);
      dst[1] = make_float4(acc[4], acc[5], acc[6], acc[7]);
      dst[2] = make_float4(acc[8], acc[9], acc[10], acc[11]);
      dst[3] = make_float4(acc[12], acc[13], acc[14], acc[15]);
    }
  }
}

// ---- gather v2: one wave per node, lane = channel; reads tpw rows
__global__ __launch_bounds__(256) void k_gather2(
    const void* __restrict__ ea, const int* __restrict__ ie,
    const int* __restrict__ offs, const int* __restrict__ eidx,
    const float* __restrict__ sup, const float* __restrict__ vup,
    const int* __restrict__ an, const float* __restrict__ cw,
    const float* __restrict__ tpw, void* __restrict__ out, int nN,
    const int* __restrict__ flagp) {
  __shared__ float B[4][960];
  const int f32 = *flagp;
  int w = threadIdx.x >> 6, l = threadIdx.x & 63;
  int n = blockIdx.x * 4 + w;
  int nn = (n < nN) ? n : 0;
  int start = offs[nn];
  int deg = offs[nn + 1] - start;

  float as0 = 0.f, as1 = 0.f;
  float av[9];
#pragma unroll
  for (int m = 0; m < 9; m++) av[m] = 0.f;

  for (int qq = 0; qq < deg; qq++) {
    int ee = __builtin_amdgcn_readfirstlane(eidx[start + qq]);
    int i  = __builtin_amdgcn_readfirstlane(ie[ee]);
    const float* tp = tpw + (size_t)ee * 320;
    float wa  = tp[l];
    float wbv = tp[64 + l];
    float wc  = tp[128 + l];
    float wd  = tp[192 + l];
    float we_ = tp[256 + l];
    float eas, ev0, ev1, ev2;
    if (f32) {
      const float4 r = ((const float4*)ea)[ee];
      eas = r.x; ev0 = r.y; ev1 = r.z; ev2 = r.w;
    } else {
      uint2 r = ((const uint2*)ea)[ee];
      eas = b2f(r.x & 0xffff); ev0 = b2f(r.x >> 16);
      ev1 = b2f(r.y & 0xffff); ev2 = b2f(r.y >> 16);
    }
    float xs  = sup[(size_t)i * 64 + l];
    float xv0 = vup[((size_t)i * 3 + 0) * 64 + l];
    float xv1 = vup[((size_t)i * 3 + 1) * 64 + l];
    float xv2 = vup[((size_t)i * 3 + 2) * 64 + l];
    float dot = xv0 * ev0 + xv1 * ev1 + xv2 * ev2;
    as0 += wa * xs * eas;
    as1 += wbv * dot * INV_SQRT3;
    float wcxs = wc * xs;
    float wde  = wd * eas;
    float wef  = we_ * INV_SQRT2;
    av[0] += wcxs * ev0; av[1] += wcxs * ev1; av[2] += wcxs * ev2;
    av[3] += wde * xv0;  av[4] += wde * xv1;  av[5] += wde * xv2;
    av[6] += wef * (xv1 * ev2 - xv2 * ev1);
    av[7] += wef * (xv2 * ev0 - xv0 * ev2);
    av[8] += wef * (xv0 * ev1 - xv1 * ev0);
  }

  // ---- node-out
  float* Bb = B[w];
  Bb[l] = as0;
  Bb[64 + l] = as1;
#pragma unroll
  for (int m = 0; m < 3; m++) {
    Bb[128 + l * 3 + m] = av[m];
    Bb[320 + l * 3 + m] = av[3 + m];
    Bb[512 + l * 3 + m] = av[6 + m];
  }
  __syncthreads();

  float s2 = 0.f;
#pragma unroll 8
  for (int c = 0; c < 128; c++) s2 += Bb[c] * cw[CW_L0 + c * 64 + l];
  float v20 = 0.f, v21 = 0.f, v22 = 0.f;
#pragma unroll 8
  for (int c = 0; c < 192; c++) {
    float wk = cw[CW_L1 + c * 64 + l];
    v20 += Bb[128 + c * 3 + 0] * wk;
    v21 += Bb[128 + c * 3 + 1] * wk;
    v22 += Bb[128 + c * 3 + 2] * wk;
  }
  int a = an[nn];
  float w01  = cw[CW_S01 + a * 64 + l];
  float w02a = cw[CW_S02 + a * 128 + l];
  float w02b = cw[CW_S02 + a * 128 + 64 + l];
  float w03a = cw[CW_S03 + a * 128 + l];
  float w03b = cw[CW_S03 + a * 128 + 64 + l];
  float w11  = cw[CW_S11 + a * 64 + l];
  float w12  = cw[CW_S12 + a * 64 + l];
  float w13a = cw[CW_S13 + a * 128 + l];
  float w13b = cw[CW_S13 + a * 128 + 64 + l];

  float vv = v20 * v20 + v21 * v21 + v22 * v22;
  float s2sq = s2 * s2;
  float vvs = vv * INV_SQRT3;
  float outs = w01 * s2 + w02a * s2sq + w02b * vvs + w03a * s2sq * s2 +
               w03b * s2 * vvs;
  float coef = w11 + w12 * s2 + w13a * s2sq + w13b * vvs;

  __syncthreads();
  Bb[704 + l] = outs;
  Bb[768 + l * 3 + 0] = coef * v20;
  Bb[768 + l * 3 + 1] = coef * v21;
  Bb[768 + l * 3 + 2] = coef * v22;
  __syncthreads();

  float so = 0.f, vo0 = 0.f, vo1 = 0.f, vo2 = 0.f;
#pragma unroll 8
  for (int c = 0; c < 64; c++) {
    float w0 = cw[CW_P0 + c * 64 + l];
    float w1 = cw[CW_P1 + c * 64 + l];
    so  += Bb[704 + c] * w0;
    vo0 += Bb[768 + c * 3 + 0] * w1;
    vo1 += Bb[768 + c * 3 + 1] * w1;
    vo2 += Bb[768 + c * 3 + 2] * w1;
  }
  if (n < nN) {
    size_t base = (size_t)n * 256;
    if (f32) {
      float* o = (float*)out;
      o[base + l] = so;
      o[base + 64 + l * 3 + 0] = vo0;
      o[base + 64 + l * 3 + 1] = vo1;
      o[base + 64 + l * 3 + 2] = vo2;
    } else {
      u16* o = (u16*)out;
      o[base + l] = f2b(so);
      o[base + 64 + l * 3 + 0] = f2b(vo0);
      o[base + 64 + l * 3 + 1] = f2b(vo1);
      o[base + 64 + l * 3 + 2] = f2b(vo2);
    }
  }
}

// ---- R3 fused gather (fallback when ws too small for tpw)
__global__ __launch_bounds__(256) void k_gather(
    const void* __restrict__ ef, const void* __restrict__ ea,
    const int* __restrict__ ie, const int* __restrict__ offs,
    const int* __restrict__ eidx, const float* __restrict__ sup,
    const float* __restrict__ vup, const int* __restrict__ an,
    const float* __restrict__ cw, void* __restrict__ out, int nN,
    const int* __restrict__ flagp) {
  __shared__ float hl[4][256];
  __shared__ float B[4][960];
  __shared__ int mdeg;
  const int f32 = *flagp;
  int w = threadIdx.x >> 6, l = threadIdx.x & 63;
  int n = blockIdx.x * 4 + w;
  int nn = (n < nN) ? n : 0;
  int start = offs[nn];
  int deg = offs[nn + 1] - start;

  if (threadIdx.x == 0) mdeg = 0;
  __syncthreads();
  if (l == 0) atomicMax(&mdeg, deg);
  __syncthreads();
  int iters = (mdeg + 3) / 4;

  float as0 = 0.f, as1 = 0.f;
  float av[9];
#pragma unroll
  for (int m = 0; m < 9; m++) av[m] = 0.f;

  for (int it = 0; it < iters; it++) {
    int c0 = it * 4;
    int cnt = deg - c0;
    if (cnt < 0) cnt = 0;
    if (cnt > 4) cnt = 4;
    int eid[4];
#pragma unroll
    for (int e = 0; e < 4; e++)
      eid[e] = (c0 + e < deg) ? eidx[start + c0 + e] : 0;

    float h[4];
#pragma unroll
    for (int e = 0; e < 4; e++) {
      float ev[8];
      if (f32) {
        const float4* p = (const float4*)ef;
        float4 q0 = p[(size_t)eid[e] * 2];
        float4 q1 = p[(size_t)eid[e] * 2 + 1];
        ev[0]=q0.x; ev[1]=q0.y; ev[2]=q0.z; ev[3]=q0.w;
        ev[4]=q1.x; ev[5]=q1.y; ev[6]=q1.z; ev[7]=q1.w;
      } else {
        const uint4* p = (const uint4*)ef;
        uint4 r = p[eid[e]];
        ev[0]=b2f(r.x & 0xffff); ev[1]=b2f(r.x >> 16);
        ev[2]=b2f(r.y & 0xffff); ev[3]=b2f(r.y >> 16);
        ev[4]=b2f(r.z & 0xffff); ev[5]=b2f(r.z >> 16);
        ev[6]=b2f(r.w & 0xffff); ev[7]=b2f(r.w >> 16);
      }
      float acc = 0.f;
#pragma unroll
      for (int b = 0; b < 8; b++) acc += ev[b] * cw[CW_M1 + b * 64 + l];
      h[e] = silu_n(acc);
    }
    *(float4*)&hl[w][l * 4] = make_float4(h[0], h[1], h[2], h[3]);
    __syncthreads();

    float a0 = 0.f, a1 = 0.f, a2 = 0.f, a3 = 0.f;
#pragma unroll 8
    for (int k = 0; k < 64; k++) {
      float4 hk = *(const float4*)&hl[w][k * 4];
      float wk = cw[CW_M2 + k * 64 + l];
      a0 += hk.x * wk; a1 += hk.y * wk; a2 += hk.z * wk; a3 += hk.w * wk;
    }
    __syncthreads();
    h[0] = silu_n(a0); h[1] = silu_n(a1); h[2] = silu_n(a2); h[3] = silu_n(a3);
    *(float4*)&hl[w][l * 4] = make_float4(h[0], h[1], h[2], h[3]);
    __syncthreads();

    a0 = a1 = a2 = a3 = 0.f;
#pragma unroll 8
    for (int k = 0; k < 64; k++) {
      float4 hk = *(const float4*)&hl[w][k * 4];
      float wk = cw[CW_M3 + k * 64 + l];
      a0 += hk.x * wk; a1 += hk.y * wk; a2 += hk.z * wk; a3 += hk.w * wk;
    }
    __syncthreads();
    h[0] = silu_n(a0); h[1] = silu_n(a1); h[2] = silu_n(a2); h[3] = silu_n(a3);
    *(float4*)&hl[w][l * 4] = make_float4(h[0], h[1], h[2], h[3]);
    __syncthreads();

    float t[5][4];
#pragma unroll
    for (int p = 0; p < 5; p++)
#pragma unroll
      for (int e = 0; e < 4; e++) t[p][e] = 0.f;
#pragma unroll 4
    for (int k = 0; k < 64; k++) {
      float4 hk = *(const float4*)&hl[w][k * 4];
      const float* wb = &cw[CW_M4 + k * 320 + l];
#pragma unroll
      for (int p = 0; p < 5; p++) {
        float wk = wb[p * 64];
        t[p][0] += hk.x * wk; t[p][1] += hk.y * wk;
        t[p][2] += hk.z * wk; t[p][3] += hk.w * wk;
      }
    }

    for (int e = 0; e < cnt; e++) {
      int ee = eid[e];
      float eas, ev0, ev1, ev2;
      if (f32) {
        const float4 r = ((const float4*)ea)[ee];
        eas = r.x; ev0 = r.y; ev1 = r.z; ev2 = r.w;
      } else {
        uint2 r = ((const uint2*)ea)[ee];
        eas = b2f(r.x & 0xffff); ev0 = b2f(r.x >> 16);
        ev1 = b2f(r.y & 0xffff); ev2 = b2f(r.y >> 16);
      }
      int i = ie[ee];
      float xs  = sup[(size_t)i * 64 + l];
      float xv0 = vup[((size_t)i * 3 + 0) * 64 + l];
      float xv1 = vup[((size_t)i * 3 + 1) * 64 + l];
      float xv2 = vup[((size_t)i * 3 + 2) * 64 + l];
      float dot = xv0 * ev0 + xv1 * ev1 + xv2 * ev2;
      as0 += t[0][e] * xs * eas;
      as1 += t[1][e] * dot * INV_SQRT3;
      float wcxs = t[2][e] * xs;
      float wde  = t[3][e] * eas;
      float wef  = t[4][e] * INV_SQRT2;
      av[0] += wcxs * ev0; av[1] += wcxs * ev1; av[2] += wcxs * ev2;
      av[3] += wde * xv0;  av[4] += wde * xv1;  av[5] += wde * xv2;
      av[6] += wef * (xv1 * ev2 - xv2 * ev1);
      av[7] += wef * (xv2 * ev0 - xv0 * ev2);
      av[8] += wef * (xv0 * ev1 - xv1 * ev0);
    }
    __syncthreads();
  }

  float* Bb = B[w];
  Bb[l] = as0;
  Bb[64 + l] = as1;
#pragma unroll
  for (int m = 0; m < 3; m++) {
    Bb[128 + l * 3 + m] = av[m];
    Bb[320 + l * 3 + m] = av[3 + m];
    Bb[512 + l * 3 + m] = av[6 + m];
  }
  __syncthreads();

  float s2 = 0.f;
#pragma unroll 8
  for (int c = 0; c < 128; c++) s2 += Bb[c] * cw[CW_L0 + c * 64 + l];
  float v20 = 0.f, v21 = 0.f, v22 = 0.f;
#pragma unroll 8
  for (int c = 0; c < 192; c++) {
    float wk = cw[CW_L1 + c * 64 + l];
    v20 += Bb[128 + c * 3 + 0] * wk;
    v21 += Bb[128 + c * 3 + 1] * wk;
    v22 += Bb[128 + c * 3 + 2] * wk;
  }
  int a = an[nn];
  float w01  = cw[CW_S01 + a * 64 + l];
  float w02a = cw[CW_S02 + a * 128 + l];
  float w02b = cw[CW_S02 + a * 128 + 64 + l];
  float w03a = cw[CW_S03 + a * 128 + l];
  float w03b = cw[CW_S03 + a * 128 + 64 + l];
  float w11  = cw[CW_S11 + a * 64 + l];
  float w12  = cw[CW_S12 + a * 64 + l];
  float w13a = cw[CW_S13 + a * 128 + l];
  float w13b = cw[CW_S13 + a * 128 + 64 + l];

  float vv = v20 * v20 + v21 * v21 + v22 * v22;
  float s2sq = s2 * s2;
  float vvs = vv * INV_SQRT3;
  float outs = w01 * s2 + w02a * s2sq + w02b * vvs + w03a * s2sq * s2 +
               w03b * s2 * vvs;
  float coef = w11 + w12 * s2 + w13a * s2sq + w13b * vvs;

  __syncthreads();
  Bb[704 + l] = outs;
  Bb[768 + l * 3 + 0] = coef * v20;
  Bb[768 + l * 3 + 1] = coef * v21;
  Bb[768 + l * 3 + 2] = coef * v22;
  __syncthreads();

  float so = 0.f, vo0 = 0.f, vo1 = 0.f, vo2 = 0.f;
#pragma unroll 8
  for (int c = 0; c < 64; c++) {
    float w0 = cw[CW_P0 + c * 64 + l];
    float w1 = cw[CW_P1 + c * 64 + l];
    so  += Bb[704 + c] * w0;
    vo0 += Bb[768 + c * 3 + 0] * w1;
    vo1 += Bb[768 + c * 3 + 1] * w1;
    vo2 += Bb[768 + c * 3 + 2] * w1;
  }
  if (n < nN) {
    size_t base = (size_t)n * 256;
    if (f32) {
      float* o = (float*)out;
      o[base + l] = so;
      o[base + 64 + l * 3 + 0] = vo0;
      o[base + 64 + l * 3 + 1] = vo1;
      o[base + 64 + l * 3 + 2] = vo2;
    } else {
      u16* o = (u16*)out;
      o[base + l] = f2b(so);
      o[base + 64 + l * 3 + 0] = f2b(vo0);
      o[base + 64 + l * 3 + 1] = f2b(vo1);
      o[base + 64 + l * 3 + 2] = f2b(vo2);
    }
  }
}

extern "C" void kernel_launch(void* const* d_in, const int* in_sizes, int n_in,
                              void* d_out, int out_size, void* d_ws,
                              size_t ws_size, hipStream_t stream) {
  const void* nf = d_in[0];
  const void* ef = d_in[1];
  const void* ea = d_in[2];
  const int* ie = (const int*)d_in[3];
  const int* je = (const int*)d_in[4];
  const int* an = (const int*)d_in[5];
  int nN = in_sizes[0] / 256;   // 20000
  int nE = in_sizes[3];         // 320000

  size_t intCnt = (size_t)3 * nN + 1 + nE;
  intCnt = (intCnt + 3) & ~(size_t)3;          // align
  int* deg    = (int*)d_ws;
  int* offs   = deg + nN;
  int* cursor = offs + nN + 1;
  int* eidx   = cursor + nN;
  float* cw   = (float*)d_ws + intCnt;
  float* sup  = cw + CW_TOTAL + CT_TOTAL;
  float* vup  = sup + (size_t)nN * 64;
  int* flag   = (int*)(vup + (size_t)nN * 192);
  size_t tpwOff = intCnt + CW_TOTAL + CT_TOTAL + (size_t)nN * 256 + 1;
  tpwOff = (tpwOff + 3) & ~(size_t)3;
  float* tpw  = (float*)d_ws + tpwOff;
  size_t need = (tpwOff + (size_t)nE * 320) * sizeof(float);
  bool big = (ws_size >= need);

  k_detect<<<1, 256, 0, stream>>>(nf, flag);
  hipMemsetAsync(deg, 0, (size_t)nN * sizeof(int), stream);

  WPtrs wp;
  const int widx[16] = {6, 7, 8, 9, 10, 11, 12, 13, 20, 21,
                        14, 15, 16, 17, 18, 19};
  for (int i = 0; i < 16; i++) wp.p[i] = d_in[widx[i]];
  k_prep<<<(CW_TOTAL + 255) / 256, 256, 0, stream>>>(wp, cw, flag);

  k_hist<<<(nE + 255) / 256, 256, 0, stream>>>(je, deg, nE);
  k_scan<<<1, 256, 0, stream>>>(deg, offs, cursor, nN);
  k_scatter<<<(nE + 255) / 256, 256, 0, stream>>>(je, cursor, eidx, nE);
  k_node_up<<<(nN + 3) / 4, 256, 0, stream>>>(nf, cw, sup, vup, nN, flag);

  if (big) {
    k_prepT<<<(CT_TOTAL + 255) / 256, 256, 0, stream>>>(cw);
    k_mlp<<<((size_t)nE * 4 + 255) / 256, 256, 0, stream>>>(ef, cw, tpw, nE,
                                                            flag);
    k_gather2<<<(nN + 3) / 4, 256, 0, stream>>>(ea, ie, offs, eidx, sup, vup,
                                                an, cw, tpw, d_out, nN, flag);
  } else {
    k_gather<<<(nN + 3) / 4, 256, 0, stream>>>(ef, ea, ie, offs, eidx, sup,
                                               vup, an, cw, d_out, nN, flag);
  }
}